// Round 8
// baseline (4328.489 us; speedup 1.0000x reference)
//
#include <hip/hip_runtime.h>
#include <hip/hip_bf16.h>
#include <hip/hip_fp16.h>
#include <cstddef>

// ---------------------------------------------------------------------------
// GCN: 3x GraphConv(norm='both') + relu + threefry dropout (p=0.5)
//   Aggregate-first identity: ndst (A (nsrc.h) W) == ndst (A (nsrc.h)) W.
//   r8 PUSH-MODE REDESIGN. r4-r7 established the pull-gather is pinned at
//   ~55us/layer by random L2-miss concurrency (84MB random-order misses,
//   insensitive to occupancy/VALU/structure). Push mode converts the same
//   bytes into SEQUENTIAL streams + XCD-local atomics:
//   - bin_k: LDS counting-sort 4096 edges by src-bucket (196x512 nodes),
//     written DIRECTLY to dense per-(bucket,xcd-group) sub-runs via split
//     cursors (cursA[x][b]: only blocks with bid&7==x touch row x -> no
//     cross-XCD cursor bouncing). Replaces binbuf+pref+debin slice-walk.
//   - srcrole_k: per bucket: dense sub-run load -> deg_out hist -> nsrc +
//     fp16 G0=nsrc*x prescale -> (stripe,slice) counting sort -> dense
//     scatterbuf runs + soff offsets.
//   - scatter_k (per layer): block (bucket b, slice sl, stripe p) on XCD p
//     (bid&7): stages its 32KB G-window into LDS SEQUENTIALLY (per-XCD G
//     read = 12.8MB streaming), then per edge fire-and-forget atomicAdd of
//     64 fp32 feats into agg[dst] -- dst in stripe p (12500 nodes, 3.2MB)
//     -> L2-resident + XCD-exclusive writes (r1 inverted). Layer 0 also
//     counts deg_in (1 atomic/edge).
//   - gemm_k (r5 dense kernel verbatim): agg -> @W(LDS) -> epilogue
//     ndst/bias/relu/threefry/2*nsrc -> fp16 G (mid) / fp32 out (final).
//   Numerics: atomic sum order differs run-to-run; noise ~ulp, tolerance
//   dominated by fp16 storage (absmax 1.2e-4). XCD-mapping assumption only
//   affects speed, never correctness.
// ---------------------------------------------------------------------------

#define EB 4096        // edges per bin_k block
#define SUBCAP 1280    // per-(bucket,xcdgroup) sub-run capacity (E[.]=1020,+8sig)
#define BCAP 10240     // per-bucket scatterbuf capacity (E[.]=8163)
#define NB_SHIFT 9
#define NB_W 512       // nodes per src-bucket
#define SW 12500       // nodes per dst-stripe (8 stripes, 3.2MB agg each)
#define WG 256

__host__ __device__ static inline unsigned rotl32(unsigned x, int r) {
  return (x << r) | (x >> (32 - r));
}

// JAX threefry2x32 block cipher (20 rounds), matches jax/_src/prng.py lowering.
__host__ __device__ static inline void threefry2x32(unsigned k0, unsigned k1,
                                                    unsigned x0, unsigned x1,
                                                    unsigned& o0, unsigned& o1) {
  unsigned ks2 = k0 ^ k1 ^ 0x1BD11BDAu;
  x0 += k0; x1 += k1;
#define TF_ROUND(r) { x0 += x1; x1 = rotl32(x1, r); x1 ^= x0; }
  TF_ROUND(13) TF_ROUND(15) TF_ROUND(26) TF_ROUND(6)
  x0 += k1;  x1 += ks2 + 1u;
  TF_ROUND(17) TF_ROUND(29) TF_ROUND(16) TF_ROUND(24)
  x0 += ks2; x1 += k0 + 2u;
  TF_ROUND(13) TF_ROUND(15) TF_ROUND(26) TF_ROUND(6)
  x0 += k0;  x1 += k1 + 3u;
  TF_ROUND(17) TF_ROUND(29) TF_ROUND(16) TF_ROUND(24)
  x0 += k1;  x1 += ks2 + 4u;
  TF_ROUND(13) TF_ROUND(15) TF_ROUND(26) TF_ROUND(6)
  x0 += ks2; x1 += k0 + 5u;
#undef TF_ROUND
  o0 = x0; o1 = x1;
}

__device__ static inline float2 h2f(unsigned u) {
  return __half22float2(__builtin_bit_cast(__half2, u));
}
__device__ static inline unsigned f2h(float a, float b) {
  return __builtin_bit_cast(unsigned, __floats2half2_rn(a, b));
}

// ---- pass 1: src-bucket counting sort, direct dense sub-run output --------
// Record: (srcloc 9b << 17) | dst 17b. Cursor cursA[x][b]: x = bid&7, so
// each cursor row is touched by only one XCD-group (no cross-XCD bouncing).

__global__ __launch_bounds__(1024) void bin_k(
    const int* __restrict__ src, const int* __restrict__ dst,
    unsigned* __restrict__ binbufA, int* __restrict__ cursA, int e) {
  __shared__ int hist[256], scan[256], curs[256], gpos[256];
  __shared__ unsigned sorted[EB];
  __shared__ unsigned char sbk[EB];
  int tid = threadIdx.x, blk = blockIdx.x;
  int base = blk * EB;
  int cnt = e - base;
  if (cnt > EB) cnt = EB;
  int x = blk & 7;

  if (tid < 256) hist[tid] = 0;
  __syncthreads();
  for (int i = tid; i < cnt; i += 1024)
    atomicAdd(&hist[src[base + i] >> NB_SHIFT], 1);
  __syncthreads();
  int h = 0;
  if (tid < 256) { h = hist[tid]; scan[tid] = h; }
  __syncthreads();
  for (int st = 1; st < 256; st <<= 1) {
    int a = 0;
    if (tid < 256 && tid >= st) a = scan[tid - st];
    __syncthreads();
    if (tid < 256) scan[tid] += a;
    __syncthreads();
  }
  if (tid < 256) curs[tid] = scan[tid] - h;   // exclusive prefix
  __syncthreads();
  for (int i = tid; i < cnt; i += 1024) {
    int s = src[base + i];
    int d = dst[base + i];
    int b = s >> NB_SHIFT;
    int p = atomicAdd(&curs[b], 1);
    sorted[p] = ((unsigned)(s & (NB_W - 1)) << 17) | (unsigned)d;
    sbk[p] = (unsigned char)b;
  }
  __syncthreads();
  if (tid < 256) {
    int c = hist[tid];
    int gp = 0;
    if (c > 0) gp = atomicAdd(&cursA[x * 256 + tid], c);
    gpos[tid] = gp;
  }
  __syncthreads();
  for (int i = tid; i < cnt; i += 1024) {
    int b = sbk[i];
    int loc = i - (scan[b] - hist[b]);
    int gp = gpos[b] + loc;
    if (gp < SUBCAP)   // overflow prob ~1e-10 (8-sigma)
      binbufA[((size_t)b * 8 + x) * SUBCAP + gp] = sorted[i];
  }
}

// ---- pass 2: per-bucket deg_out/nsrc/G0-prescale + (stripe,slice) sort ----

__global__ __launch_bounds__(1024) void srcrole_k(
    const unsigned* __restrict__ binbufA, const int* __restrict__ cursA,
    float* __restrict__ nsrc, const float* __restrict__ x,
    unsigned short* __restrict__ G0, unsigned* __restrict__ scatterbuf,
    unsigned short* __restrict__ soff, int n) {
  __shared__ unsigned eb[BCAP];
  __shared__ int lcnt[NB_W];
  __shared__ float lns[NB_W];
  __shared__ int kh[16], ko[17], kc[16];
  __shared__ int cx[8], ox[9];
  int tid = threadIdx.x, b = blockIdx.x;

  if (tid < 8) {
    int c = cursA[tid * 256 + b];
    cx[tid] = (c > SUBCAP) ? SUBCAP : c;
  }
  for (int i = tid; i < NB_W; i += 1024) lcnt[i] = 0;
  if (tid < 16) kh[tid] = 0;
  __syncthreads();
  if (tid == 0) {
    int o = 0;
    for (int i = 0; i < 8; ++i) { ox[i] = o; o += cx[i]; }
    ox[8] = o;
  }
  __syncthreads();
  int tot = ox[8];
  for (int xx = 0; xx < 8; ++xx) {
    int c = cx[xx];
    const unsigned* sp = binbufA + ((size_t)b * 8 + xx) * SUBCAP;
    int ob = ox[xx];
    for (int i = tid; i < c; i += 1024) eb[ob + i] = sp[i];
  }
  __syncthreads();
  for (int i = tid; i < tot; i += 1024) atomicAdd(&lcnt[eb[i] >> 17], 1);
  __syncthreads();
  int vbase = b << NB_SHIFT;
  for (int i = tid; i < NB_W; i += 1024) {
    int v = vbase + i;
    if (v < n) {
      int c = lcnt[i];
      float ns = (c > 0) ? rsqrtf((float)c) : 0.f;
      lns[i] = ns;
      nsrc[v] = ns;
    }
  }
  __syncthreads();
  // fp16 G0 = nsrc * x, coalesced
  const float4* x4 = (const float4*)x;
  uint2* G2 = (uint2*)G0;
  for (int idx = tid; idx < NB_W * 16; idx += 1024) {
    int i = idx >> 4;
    int v = vbase + i;
    if (v < n) {
      float ns = lns[i];
      float4 r = x4[(size_t)v * 16 + (idx & 15)];
      G2[(size_t)v * 16 + (idx & 15)] =
          make_uint2(f2h(r.x * ns, r.y * ns), f2h(r.z * ns, r.w * ns));
    }
  }
  // (stripe,slice) counting sort within bucket
  for (int i = tid; i < tot; i += 1024) {
    unsigned e = eb[i];
    int d = e & 0x1FFFF;
    int k = ((d / SW) << 1) | ((e >> 25) & 1);   // stripe | srcloc-half
    atomicAdd(&kh[k], 1);
  }
  __syncthreads();
  if (tid == 0) {
    int o = 0;
    for (int k = 0; k < 16; ++k) { ko[k] = o; kc[k] = 0; o += kh[k]; }
    ko[16] = o;
  }
  __syncthreads();
  if (tid < 17) soff[b * 17 + tid] = (unsigned short)ko[tid];
  for (int i = tid; i < tot; i += 1024) {
    unsigned e = eb[i];
    int srcloc = e >> 17;
    int d = e & 0x1FFFF;
    int st = d / SW;
    int dl = d - st * SW;
    int k = (st << 1) | ((srcloc >> 8) & 1);
    int p = ko[k] + atomicAdd(&kc[k], 1);
    scatterbuf[(size_t)b * BCAP + p] = ((unsigned)srcloc << 14) | (unsigned)dl;
  }
}

// ---- per-layer pass A: sequential window stage + stripe-local scatter -----
// Block (b, sl, p), bid = ((b*2+sl)<<3)|p -> XCD p. Stages G rows
// [b*512+sl*256, +256) (32KB) to LDS sequentially, then per edge a 16-lane
// group atomicAdds 64 fp32 feats into agg[stripe-p-local dst].

__global__ __launch_bounds__(WG) void scatter_k(
    const unsigned short* __restrict__ G, const unsigned* __restrict__ scatterbuf,
    const unsigned short* __restrict__ soff, float* __restrict__ agg,
    int* __restrict__ cnt_in, int dflag) {
  __shared__ unsigned win[256 * 32];   // 32 KB: 256 rows x 64 fp16
  int bid = blockIdx.x;
  int p = bid & 7;
  int t = bid >> 3;
  int b = t >> 1;
  int sl = t & 1;
  int tid = threadIdx.x;

  const uint4* Gv = (const uint4*)(G + ((size_t)(b * NB_W + sl * 256)) * 64);
  uint4* wv = (uint4*)win;
  for (int i = tid; i < 2048; i += WG) wv[i] = Gv[i];

  int key = (p << 1) | sl;
  int o0 = soff[b * 17 + key];
  int o1 = soff[b * 17 + key + 1];
  __syncthreads();

  int ne = o1 - o0;
  const unsigned* ebase = scatterbuf + (size_t)b * BCAP + o0;
  int grp = tid >> 4;
  int l16 = tid & 15;
  int vstripe = p * SW;
  for (int i = grp; i < ne; i += 16) {
    unsigned e = ebase[i];
    int row = (e >> 14) & 255;
    int dl = e & 0x3FFF;
    uint2 m = *(const uint2*)&win[row * 32 + l16 * 2];
    float2 lo = h2f(m.x), hi = h2f(m.y);
    float* ap = agg + ((size_t)(vstripe + dl)) * 64 + l16 * 4;
    atomicAdd(ap + 0, lo.x);
    atomicAdd(ap + 1, lo.y);
    atomicAdd(ap + 2, hi.x);
    atomicAdd(ap + 3, hi.y);
    if (dflag && l16 == 0) atomicAdd(&cnt_in[vstripe + dl], 1);
  }
}

// ---- per-layer pass B: dense agg @ W + epilogue (r5 kernel) ---------------

__global__ __launch_bounds__(WG) void gemm_k(
    const float* __restrict__ agg, const int* __restrict__ cnt_in,
    const float* __restrict__ nsrc, const float* __restrict__ W,
    const float* __restrict__ bias,
    unsigned short* __restrict__ GoutH, float* __restrict__ GoutF,
    int n, int mid, unsigned dk0, unsigned dk1) {
  __shared__ float4 Ws[1024];                  // 16 KB W[k][j]
  __shared__ __align__(16) float rows[4][272]; // 4 waves x (4 rows @ 68)
  const float4* W4 = (const float4*)W;
  for (int i = threadIdx.x; i < 1024; i += WG) Ws[i] = W4[i];

  int wave = threadIdx.x >> 6;
  int lane = threadIdx.x & 63;
  int g = lane >> 4;
  int l16 = lane & 15;
  int v = blockIdx.x * 16 + wave * 4 + g;
  bool valid = (v < n);
  int vc = valid ? v : (n - 1);

  int degt = valid ? cnt_in[vc] : 0;
  float4 a4 = ((const float4*)agg)[(size_t)vc * 16 + l16];

  float* rw = &rows[wave][g * 68];
  *(float4*)(rw + l16 * 4) = a4;
  __syncthreads();   // covers Ws staging + rows staging

  float4 acc = make_float4(0.f, 0.f, 0.f, 0.f);
#pragma unroll
  for (int k = 0; k < 64; ++k) {
    float a = rw[k];
    float4 w = Ws[k * 16 + l16];
    acc.x = fmaf(a, w.x, acc.x);
    acc.y = fmaf(a, w.y, acc.y);
    acc.z = fmaf(a, w.z, acc.z);
    acc.w = fmaf(a, w.w, acc.w);
  }

  float nd = (degt > 0) ? rsqrtf((float)degt) : 0.f;
  float4 b4 = ((const float4*)bias)[l16];
  float4 o;
  o.x = fmaf(acc.x, nd, b4.x);
  o.y = fmaf(acc.y, nd, b4.y);
  o.z = fmaf(acc.z, nd, b4.z);
  o.w = fmaf(acc.w, nd, b4.w);
  if (mid) {
    o.x = fmaxf(o.x, 0.f); o.y = fmaxf(o.y, 0.f);
    o.z = fmaxf(o.z, 0.f); o.w = fmaxf(o.w, 0.f);
    unsigned idx = (unsigned)(v * 64 + l16 * 4);
    unsigned r0a, r0b, r1a, r1b, r2a, r2b, r3a, r3b;
    threefry2x32(dk0, dk1, 0u, idx + 0u, r0a, r0b);
    threefry2x32(dk0, dk1, 0u, idx + 1u, r1a, r1b);
    threefry2x32(dk0, dk1, 0u, idx + 2u, r2a, r2b);
    threefry2x32(dk0, dk1, 0u, idx + 3u, r3a, r3b);
    float ns2 = 2.f * nsrc[vc];   // dropout keep-scale x next-layer nsrc
    o.x = ((r0a ^ r0b) & 0x80000000u) ? 0.f : o.x * ns2;
    o.y = ((r1a ^ r1b) & 0x80000000u) ? 0.f : o.y * ns2;
    o.z = ((r2a ^ r2b) & 0x80000000u) ? 0.f : o.z * ns2;
    o.w = ((r3a ^ r3b) & 0x80000000u) ? 0.f : o.w * ns2;
    if (valid)
      ((uint2*)GoutH)[(size_t)v * 16 + l16] =
          make_uint2(f2h(o.x, o.y), f2h(o.z, o.w));
  } else {
    if (valid) ((float4*)GoutF)[(size_t)v * 16 + l16] = o;
  }
}

// ---------------------------------------------------------------------------

extern "C" void kernel_launch(void* const* d_in, const int* in_sizes, int n_in,
                              void* d_out, int out_size, void* d_ws, size_t ws_size,
                              hipStream_t stream) {
  const float* x  = (const float*)d_in[0];
  const float* W0 = (const float*)d_in[1];
  const float* b0 = (const float*)d_in[2];
  const float* W1 = (const float*)d_in[3];
  const float* b1 = (const float*)d_in[4];
  const float* W2 = (const float*)d_in[5];
  const float* b2 = (const float*)d_in[6];
  const int* src  = (const int*)d_in[7];
  const int* dst  = (const int*)d_in[8];
  float* out = (float*)d_out;

  const int n = in_sizes[0] / 64;   // 100000
  const int e = in_sizes[7];        // 1600000
  const int nbuck = (n + NB_W - 1) / NB_W;   // 196
  const int nblk = (e + EB - 1) / EB;        // 391
  const size_t padrows = (size_t)nbuck * NB_W;   // 100352 (window padding)

  char* w = (char*)d_ws;
  size_t off = 0;
  auto alloc = [&](size_t bytes) -> void* {
    void* p = w + off;
    off += (bytes + 255) & ~(size_t)255;
    return p;
  };
  int*            cnt_in     = (int*)alloc((size_t)n * 4);
  float*          nsrc       = (float*)alloc((size_t)n * 4);
  int*            cursA      = (int*)alloc((size_t)8 * 256 * 4);
  unsigned*       binbufA    = (unsigned*)alloc((size_t)nbuck * 8 * SUBCAP * 4); // 8.0 MB
  unsigned*       scatterbuf = (unsigned*)alloc((size_t)nbuck * BCAP * 4);       // 8.0 MB
  unsigned short* soff       = (unsigned short*)alloc((size_t)nbuck * 17 * 2);
  unsigned short* G0         = (unsigned short*)alloc(padrows * 64 * 2);         // 12.85 MB
  unsigned short* G1         = (unsigned short*)alloc(padrows * 64 * 2);         // 12.85 MB
  float*          aggbuf     = (float*)alloc((size_t)n * 64 * 4);                // 25.6 MB

  unsigned k0a, k0b, k1a, k1b;
  threefry2x32(0u, 1u, 0u, 0u, k0a, k0b);
  threefry2x32(0u, 1u, 0u, 1u, k1a, k1b);

  const int gS = nbuck * 2 * 8;        // scatter: 3136 blocks
  const int gG = (n + 15) / 16;        // gemm: 6250 blocks

  hipMemsetAsync(cnt_in, 0, (size_t)n * 4, stream);
  hipMemsetAsync(cursA, 0, (size_t)8 * 256 * 4, stream);

  bin_k<<<nblk, 1024, 0, stream>>>(src, dst, binbufA, cursA, e);
  srcrole_k<<<nbuck, 1024, 0, stream>>>(binbufA, cursA, nsrc, x, G0,
                                        scatterbuf, soff, n);

  // layer 0: push G0 -> agg -> fp16 G1 (relu+drop key0, x 2*nsrc); deg_in
  hipMemsetAsync(aggbuf, 0, (size_t)n * 64 * 4, stream);
  scatter_k<<<gS, WG, 0, stream>>>(G0, scatterbuf, soff, aggbuf, cnt_in, 1);
  gemm_k<<<gG, WG, 0, stream>>>(aggbuf, cnt_in, nsrc, W0, b0,
                                G1, nullptr, n, 1, k0a, k0b);
  // layer 1: push G1 -> agg -> fp16 G0 (relu+drop key1, x 2*nsrc)
  hipMemsetAsync(aggbuf, 0, (size_t)n * 64 * 4, stream);
  scatter_k<<<gS, WG, 0, stream>>>(G1, scatterbuf, soff, aggbuf, cnt_in, 0);
  gemm_k<<<gG, WG, 0, stream>>>(aggbuf, cnt_in, nsrc, W1, b1,
                                G0, nullptr, n, 1, k1a, k1b);
  // layer 2: push G0 -> agg -> fp32 d_out (final)
  hipMemsetAsync(aggbuf, 0, (size_t)n * 64 * 4, stream);
  scatter_k<<<gS, WG, 0, stream>>>(G0, scatterbuf, soff, aggbuf, cnt_in, 0);
  gemm_k<<<gG, WG, 0, stream>>>(aggbuf, cnt_in, nsrc, W2, b2,
                                nullptr, out, n, 0, 0u, 0u);
}

// Round 9
// 264.523 us; speedup vs baseline: 16.3634x; 16.3634x over previous
//
#include <hip/hip_runtime.h>
#include <hip/hip_bf16.h>
#include <hip/hip_fp16.h>
#include <cstddef>

// ---------------------------------------------------------------------------
// GCN: 3x GraphConv(norm='both') + relu + threefry dropout (p=0.5)
//   Aggregate-first identity: ndst (A (nsrc.h) W) == ndst (A (nsrc.h)) W.
//   Gather buffers G are FP16 row-major; all accumulation stays FP32.
//
//   r9 = r7 fused pull layers (best known, 266us) + dense-run preprocessing
//   derived from r8's verified binning:
//   - bin_k: per 4096-edge block, LDS counting-sort by dst-bucket AND
//     src-bucket; records written DIRECTLY to dense per-(bucket,xcd-group)
//     sub-runs via split global cursors (curs[x][b] touched only by blocks
//     with bid&7==x -> no cross-XCD cursor lines bouncing). Replaces
//     binbuf + pref tables.
//   - role_k: dst role = read bucket's 8 dense sub-runs coalesced, LDS
//     cursor scatter -> slot rows + cnt_in (bucket-owner writes, 98KB
//     region per block). src role = dense read -> deg hist -> nsrc + fp16
//     G0 = nsrc*x prescale. Replaces r7 debin's 391-tiny-slice walk
//     (~84B dependent loads), its measured ~55us cost.
//   - layer_k (r7 verbatim, characterized floor ~55us): wave = 4 nodes;
//     16-lane group gathers in-edge fp16 rows (uint2/lane, 128B/row), fp32
//     reduce, LDS stage, 64-step FMA vs LDS fp32 W, epilogue ndst/bias/
//     relu/threefry/2*nsrc; mid->fp16 G, final->fp32 out.
//   History: r1/r8 = per-feature global atomics amplify writes 7.5-65x
//   (never again); r4 threefry hoist serialized; r5 split + r6 slicing
//   neutral-to-negative: gather is random-miss-concurrency bound at
//   ~55us/layer regardless of occupancy/VALU/structure.
// ---------------------------------------------------------------------------

#define EB 4096        // edges per bin_k block
#define SUBCAP 1280    // per-(bucket,xcdgroup) sub-run cap (E=1020, +8 sigma)
#define NB_SHIFT 9
#define NB_W 512       // nodes per bucket
#define SLOT_S 48      // max tracked in-degree; P(Poisson(16) >= 48) ~ 5e-11
#define WG 256

__host__ __device__ static inline unsigned rotl32(unsigned x, int r) {
  return (x << r) | (x >> (32 - r));
}

// JAX threefry2x32 block cipher (20 rounds), matches jax/_src/prng.py lowering.
__host__ __device__ static inline void threefry2x32(unsigned k0, unsigned k1,
                                                    unsigned x0, unsigned x1,
                                                    unsigned& o0, unsigned& o1) {
  unsigned ks2 = k0 ^ k1 ^ 0x1BD11BDAu;
  x0 += k0; x1 += k1;
#define TF_ROUND(r) { x0 += x1; x1 = rotl32(x1, r); x1 ^= x0; }
  TF_ROUND(13) TF_ROUND(15) TF_ROUND(26) TF_ROUND(6)
  x0 += k1;  x1 += ks2 + 1u;
  TF_ROUND(17) TF_ROUND(29) TF_ROUND(16) TF_ROUND(24)
  x0 += ks2; x1 += k0 + 2u;
  TF_ROUND(13) TF_ROUND(15) TF_ROUND(26) TF_ROUND(6)
  x0 += k0;  x1 += k1 + 3u;
  TF_ROUND(17) TF_ROUND(29) TF_ROUND(16) TF_ROUND(24)
  x0 += k1;  x1 += ks2 + 4u;
  TF_ROUND(13) TF_ROUND(15) TF_ROUND(26) TF_ROUND(6)
  x0 += ks2; x1 += k0 + 5u;
#undef TF_ROUND
  o0 = x0; o1 = x1;
}

__device__ static inline float2 h2f(unsigned u) {
  return __half22float2(__builtin_bit_cast(__half2, u));
}
__device__ static inline unsigned f2h(float a, float b) {
  return __builtin_bit_cast(unsigned, __floats2half2_rn(a, b));
}

// ---- pass 1: dual LDS counting-sort -> dense per-(bucket,xcdgrp) sub-runs -
// dst record: (dstloc 9b << 17) | src 17b.  src record: (srcloc<<17) | dst.

__global__ __launch_bounds__(1024) void bin_k(
    const int* __restrict__ src, const int* __restrict__ dst,
    unsigned* __restrict__ binbufD, unsigned* __restrict__ binbufS,
    int* __restrict__ cursD, int* __restrict__ cursS, int e) {
  __shared__ int hist_d[256], scan_d[256], curs_d[256], gpos_d[256];
  __shared__ int hist_s[256], scan_s[256], curs_s[256], gpos_s[256];
  __shared__ unsigned sorted_d[EB], sorted_s[EB];
  __shared__ unsigned char sbk_d[EB], sbk_s[EB];
  int tid = threadIdx.x, blk = blockIdx.x;
  int base = blk * EB;
  int cnt = e - base;
  if (cnt > EB) cnt = EB;
  int x = blk & 7;

  if (tid < 256) { hist_d[tid] = 0; hist_s[tid] = 0; }
  __syncthreads();
  for (int i = tid; i < cnt; i += 1024) {
    atomicAdd(&hist_d[dst[base + i] >> NB_SHIFT], 1);
    atomicAdd(&hist_s[src[base + i] >> NB_SHIFT], 1);
  }
  __syncthreads();
  int hd = 0, hs = 0;
  if (tid < 256) {
    hd = hist_d[tid]; scan_d[tid] = hd;
    hs = hist_s[tid]; scan_s[tid] = hs;
  }
  __syncthreads();
  for (int st = 1; st < 256; st <<= 1) {
    int ad = 0, as = 0;
    if (tid < 256 && tid >= st) { ad = scan_d[tid - st]; as = scan_s[tid - st]; }
    __syncthreads();
    if (tid < 256) { scan_d[tid] += ad; scan_s[tid] += as; }
    __syncthreads();
  }
  if (tid < 256) { curs_d[tid] = scan_d[tid] - hd; curs_s[tid] = scan_s[tid] - hs; }
  __syncthreads();
  for (int i = tid; i < cnt; i += 1024) {
    int s = src[base + i];
    int d = dst[base + i];
    int bd = d >> NB_SHIFT;
    int pd = atomicAdd(&curs_d[bd], 1);
    sorted_d[pd] = ((unsigned)(d & (NB_W - 1)) << 17) | (unsigned)s;
    sbk_d[pd] = (unsigned char)bd;
    int bs = s >> NB_SHIFT;
    int ps = atomicAdd(&curs_s[bs], 1);
    sorted_s[ps] = ((unsigned)(s & (NB_W - 1)) << 17) | (unsigned)d;
    sbk_s[ps] = (unsigned char)bs;
  }
  __syncthreads();
  if (tid < 256) {
    int c = hist_d[tid];
    gpos_d[tid] = (c > 0) ? atomicAdd(&cursD[x * 256 + tid], c) : 0;
    c = hist_s[tid];
    gpos_s[tid] = (c > 0) ? atomicAdd(&cursS[x * 256 + tid], c) : 0;
  }
  __syncthreads();
  for (int i = tid; i < cnt; i += 1024) {
    int b = sbk_d[i];
    int gp = gpos_d[b] + (i - (scan_d[b] - hist_d[b]));
    if (gp < SUBCAP)   // overflow prob ~1e-10
      binbufD[((size_t)b * 8 + x) * SUBCAP + gp] = sorted_d[i];
    b = sbk_s[i];
    gp = gpos_s[b] + (i - (scan_s[b] - hist_s[b]));
    if (gp < SUBCAP)
      binbufS[((size_t)b * 8 + x) * SUBCAP + gp] = sorted_s[i];
  }
}

// ---- pass 2: per-bucket dense-run consumption ------------------------------
// b < nbuck: dst role -> slot rows + cnt_in. else: src role -> nsrc + G0.

__global__ __launch_bounds__(1024) void role_k(
    const unsigned* __restrict__ binbufD, const unsigned* __restrict__ binbufS,
    const int* __restrict__ cursD, const int* __restrict__ cursS,
    int* __restrict__ slot, int* __restrict__ cnt_in,
    float* __restrict__ nsrc, const float* __restrict__ x,
    unsigned short* __restrict__ G0, int n, int nbuck) {
  __shared__ int lcur[NB_W];
  __shared__ float lns[NB_W];
  __shared__ int cx[8];
  int tid = threadIdx.x;
  int bb = blockIdx.x;
  int role = (bb < nbuck) ? 0 : 1;
  int b = role ? (bb - nbuck) : bb;

  const int* cursX = role ? cursS : cursD;
  if (tid < 8) {
    int c = cursX[tid * 256 + b];
    cx[tid] = (c > SUBCAP) ? SUBCAP : c;
  }
  for (int i = tid; i < NB_W; i += 1024) lcur[i] = 0;
  __syncthreads();

  if (role == 0) {
    // dst role: 8 dense coalesced sub-runs -> LDS cursor -> slot + cnt_in
    for (int xx = 0; xx < 8; ++xx) {
      int c = cx[xx];
      const unsigned* sp = binbufD + ((size_t)b * 8 + xx) * SUBCAP;
      for (int i = tid; i < c; i += 1024) {
        unsigned v = sp[i];
        int dl = v >> 17;
        int s = (int)(v & 0x1FFFFu);
        int cc = atomicAdd(&lcur[dl], 1);
        if (cc < SLOT_S) slot[(size_t)((b << NB_SHIFT) + dl) * SLOT_S + cc] = s;
      }
    }
    __syncthreads();
    for (int i = tid; i < NB_W; i += 1024) {
      int v = (b << NB_SHIFT) + i;
      if (v < n) cnt_in[v] = lcur[i];
    }
  } else {
    // src role: dense hist -> nsrc + fp16 G0 = nsrc*x prescale
    for (int xx = 0; xx < 8; ++xx) {
      int c = cx[xx];
      const unsigned* sp = binbufS + ((size_t)b * 8 + xx) * SUBCAP;
      for (int i = tid; i < c; i += 1024) atomicAdd(&lcur[sp[i] >> 17], 1);
    }
    __syncthreads();
    int vbase = b << NB_SHIFT;
    for (int i = tid; i < NB_W; i += 1024) {
      int v = vbase + i;
      if (v < n) {
        int c = lcur[i];
        float ns = (c > 0) ? rsqrtf((float)c) : 0.f;
        lns[i] = ns;
        nsrc[v] = ns;
      }
    }
    __syncthreads();
    const float4* x4 = (const float4*)x;
    uint2* G2 = (uint2*)G0;
    for (int idx = tid; idx < NB_W * 16; idx += 1024) {
      int i = idx >> 4;
      int v = vbase + i;
      if (v < n) {
        float ns = lns[i];
        float4 r = x4[(size_t)v * 16 + (idx & 15)];
        G2[(size_t)v * 16 + (idx & 15)] =
            make_uint2(f2h(r.x * ns, r.y * ns), f2h(r.z * ns, r.w * ns));
      }
    }
  }
}

// ---- fused per-layer kernel: fp16 gather -> fp32 @W -> epilogue -----------
// Wave = 4 nodes (16-lane group per node). Group gathers its node's in-edge
// fp16 rows from G (uint2 = 4 feats/lane, 128B/row), fp32-reduces, stages to
// LDS, 64-step FMA with LDS-resident fp32 W, then epilogue:
// *ndst+bias [, relu, threefry-drop, *2*nsrc]. Mid -> fp16 Gout; final -> f32.
__global__ __launch_bounds__(WG) void layer_k(
    const unsigned short* __restrict__ G, const int* __restrict__ slot,
    const int* __restrict__ cnt_in, const float* __restrict__ nsrc,
    const float* __restrict__ W, const float* __restrict__ bias,
    unsigned short* __restrict__ GoutH, float* __restrict__ GoutF,
    int n, int mid, unsigned dk0, unsigned dk1) {
  __shared__ float4 Ws[1024];                  // 16 KB W[k][j]
  __shared__ __align__(16) float rows[4][272]; // 4 waves x (4 rows @ 68)
  const float4* W4 = (const float4*)W;
  for (int i = threadIdx.x; i < 1024; i += WG) Ws[i] = W4[i];

  int wave = threadIdx.x >> 6;
  int lane = threadIdx.x & 63;
  int g = lane >> 4;
  int l16 = lane & 15;
  int v = blockIdx.x * 16 + wave * 4 + g;
  bool valid = (v < n);
  int vc = valid ? v : (n - 1);

  int degt = valid ? cnt_in[vc] : 0;
  int deg = (degt > SLOT_S) ? SLOT_S : degt;
  const int* sl = slot + (size_t)vc * SLOT_S;
  const uint2* G2 = (const uint2*)G;

  float4 aA = make_float4(0.f, 0.f, 0.f, 0.f);
  float4 aB = make_float4(0.f, 0.f, 0.f, 0.f);
  float4 aC = make_float4(0.f, 0.f, 0.f, 0.f);
  float4 aD = make_float4(0.f, 0.f, 0.f, 0.f);
#define ACC(dst, m) { float2 lo = h2f((m).x), hi = h2f((m).y); \
    dst.x += lo.x; dst.y += lo.y; dst.z += hi.x; dst.w += hi.y; }
  int nq = deg >> 2;
  int i = 0;
  for (; i + 1 < nq; i += 2) {   // 2 quads = 8 gathers in flight per group
    int4 q0 = *(const int4*)(sl + i * 4);
    int4 q1 = *(const int4*)(sl + i * 4 + 4);
    uint2 m0 = G2[(size_t)q0.x * 16 + l16];
    uint2 m1 = G2[(size_t)q0.y * 16 + l16];
    uint2 m2 = G2[(size_t)q0.z * 16 + l16];
    uint2 m3 = G2[(size_t)q0.w * 16 + l16];
    uint2 m4 = G2[(size_t)q1.x * 16 + l16];
    uint2 m5 = G2[(size_t)q1.y * 16 + l16];
    uint2 m6 = G2[(size_t)q1.z * 16 + l16];
    uint2 m7 = G2[(size_t)q1.w * 16 + l16];
    ACC(aA, m0) ACC(aB, m1) ACC(aC, m2) ACC(aD, m3)
    ACC(aA, m4) ACC(aB, m5) ACC(aC, m6) ACC(aD, m7)
  }
  if (i < nq) {
    int4 q0 = *(const int4*)(sl + i * 4);
    uint2 m0 = G2[(size_t)q0.x * 16 + l16];
    uint2 m1 = G2[(size_t)q0.y * 16 + l16];
    uint2 m2 = G2[(size_t)q0.z * 16 + l16];
    uint2 m3 = G2[(size_t)q0.w * 16 + l16];
    ACC(aA, m0) ACC(aB, m1) ACC(aC, m2) ACC(aD, m3)
  }
  int rem = deg & 3;
  if (rem) {   // fma-masked tail quad; slot row memory-safe (SLOT_S mult of 4)
    int4 qq = *(const int4*)(sl + (deg & ~3));
    int s0 = qq.x;                        // rem >= 1
    int s1 = (rem > 1) ? qq.y : s0;
    int s2 = (rem > 2) ? qq.z : s0;
    float w1 = (rem > 1) ? 1.f : 0.f;
    float w2 = (rem > 2) ? 1.f : 0.f;
    uint2 m0 = G2[(size_t)s0 * 16 + l16];
    uint2 m1 = G2[(size_t)s1 * 16 + l16];
    uint2 m2 = G2[(size_t)s2 * 16 + l16];
    ACC(aA, m0)
    { float2 lo = h2f(m1.x), hi = h2f(m1.y);
      aB.x = fmaf(w1, lo.x, aB.x); aB.y = fmaf(w1, lo.y, aB.y);
      aB.z = fmaf(w1, hi.x, aB.z); aB.w = fmaf(w1, hi.y, aB.w); }
    { float2 lo = h2f(m2.x), hi = h2f(m2.y);
      aC.x = fmaf(w2, lo.x, aC.x); aC.y = fmaf(w2, lo.y, aC.y);
      aC.z = fmaf(w2, hi.x, aC.z); aC.w = fmaf(w2, hi.y, aC.w); }
  }
#undef ACC
  float4 agg;
  agg.x = (aA.x + aB.x) + (aC.x + aD.x);
  agg.y = (aA.y + aB.y) + (aC.y + aD.y);
  agg.z = (aA.z + aB.z) + (aC.z + aD.z);
  agg.w = (aA.w + aB.w) + (aC.w + aD.w);

  float* rw = &rows[wave][g * 68];
  *(float4*)(rw + l16 * 4) = agg;
  __syncthreads();   // covers Ws staging + rows staging

  float4 acc = make_float4(0.f, 0.f, 0.f, 0.f);
#pragma unroll
  for (int k = 0; k < 64; ++k) {
    float a = rw[k];
    float4 w = Ws[k * 16 + l16];
    acc.x = fmaf(a, w.x, acc.x);
    acc.y = fmaf(a, w.y, acc.y);
    acc.z = fmaf(a, w.z, acc.z);
    acc.w = fmaf(a, w.w, acc.w);
  }

  float nd = (degt > 0) ? rsqrtf((float)degt) : 0.f;
  float4 b4 = ((const float4*)bias)[l16];
  float4 o;
  o.x = fmaf(acc.x, nd, b4.x);
  o.y = fmaf(acc.y, nd, b4.y);
  o.z = fmaf(acc.z, nd, b4.z);
  o.w = fmaf(acc.w, nd, b4.w);
  if (mid) {
    o.x = fmaxf(o.x, 0.f); o.y = fmaxf(o.y, 0.f);
    o.z = fmaxf(o.z, 0.f); o.w = fmaxf(o.w, 0.f);
    unsigned idx = (unsigned)(v * 64 + l16 * 4);
    unsigned r0a, r0b, r1a, r1b, r2a, r2b, r3a, r3b;
    threefry2x32(dk0, dk1, 0u, idx + 0u, r0a, r0b);
    threefry2x32(dk0, dk1, 0u, idx + 1u, r1a, r1b);
    threefry2x32(dk0, dk1, 0u, idx + 2u, r2a, r2b);
    threefry2x32(dk0, dk1, 0u, idx + 3u, r3a, r3b);
    float ns2 = 2.f * nsrc[vc];   // dropout keep-scale x next-layer nsrc
    o.x = ((r0a ^ r0b) & 0x80000000u) ? 0.f : o.x * ns2;
    o.y = ((r1a ^ r1b) & 0x80000000u) ? 0.f : o.y * ns2;
    o.z = ((r2a ^ r2b) & 0x80000000u) ? 0.f : o.z * ns2;
    o.w = ((r3a ^ r3b) & 0x80000000u) ? 0.f : o.w * ns2;
    if (valid)
      ((uint2*)GoutH)[(size_t)v * 16 + l16] =
          make_uint2(f2h(o.x, o.y), f2h(o.z, o.w));
  } else {
    if (valid) ((float4*)GoutF)[(size_t)v * 16 + l16] = o;
  }
}

// ---------------------------------------------------------------------------

extern "C" void kernel_launch(void* const* d_in, const int* in_sizes, int n_in,
                              void* d_out, int out_size, void* d_ws, size_t ws_size,
                              hipStream_t stream) {
  const float* x  = (const float*)d_in[0];
  const float* W0 = (const float*)d_in[1];
  const float* b0 = (const float*)d_in[2];
  const float* W1 = (const float*)d_in[3];
  const float* b1 = (const float*)d_in[4];
  const float* W2 = (const float*)d_in[5];
  const float* b2 = (const float*)d_in[6];
  const int* src  = (const int*)d_in[7];
  const int* dst  = (const int*)d_in[8];
  float* out = (float*)d_out;

  const int n = in_sizes[0] / 64;   // 100000
  const int e = in_sizes[7];        // 1600000
  const int nbuck = (n + NB_W - 1) / NB_W;   // 196
  const int nblk = (e + EB - 1) / EB;        // 391

  char* w = (char*)d_ws;
  size_t off = 0;
  auto alloc = [&](size_t bytes) -> void* {
    void* p = w + off;
    off += (bytes + 255) & ~(size_t)255;
    return p;
  };
  int*            cnt_in  = (int*)alloc((size_t)n * 4);
  float*          nsrc    = (float*)alloc((size_t)n * 4);
  int*            cursD   = (int*)alloc((size_t)8 * 256 * 4);
  int*            cursS   = (int*)alloc((size_t)8 * 256 * 4);
  unsigned*       binbufD = (unsigned*)alloc((size_t)nbuck * 8 * SUBCAP * 4); // 8.0 MB
  unsigned*       binbufS = (unsigned*)alloc((size_t)nbuck * 8 * SUBCAP * 4); // 8.0 MB
  int*            slot    = (int*)alloc((size_t)nbuck * NB_W * SLOT_S * 4);   // 19.3 MB
  unsigned short* G0      = (unsigned short*)alloc((size_t)n * 64 * 2);       // 12.8 MB
  unsigned short* G1      = (unsigned short*)alloc((size_t)n * 64 * 2);       // 12.8 MB

  unsigned k0a, k0b, k1a, k1b;
  threefry2x32(0u, 1u, 0u, 0u, k0a, k0b);
  threefry2x32(0u, 1u, 0u, 1u, k1a, k1b);

  const int gL = (n + 15) / 16;   // layer: 16 nodes/block

  hipMemsetAsync(cursD, 0, (size_t)8 * 256 * 4, stream);
  hipMemsetAsync(cursS, 0, (size_t)8 * 256 * 4, stream);

  bin_k<<<nblk, 1024, 0, stream>>>(src, dst, binbufD, binbufS,
                                   cursD, cursS, e);
  role_k<<<2 * nbuck, 1024, 0, stream>>>(binbufD, binbufS, cursD, cursS,
                                         slot, cnt_in, nsrc, x, G0, n, nbuck);

  // layer 0: gather G0 -> fp16 G1   (relu+drop key0, x 2*nsrc)
  layer_k<<<gL, WG, 0, stream>>>(G0, slot, cnt_in, nsrc, W0, b0, G1, nullptr,
                                 n, 1, k0a, k0b);
  // layer 1: gather G1 -> fp16 G0   (relu+drop key1, x 2*nsrc)
  layer_k<<<gL, WG, 0, stream>>>(G1, slot, cnt_in, nsrc, W1, b1, G0, nullptr,
                                 n, 1, k1a, k1b);
  // layer 2: gather G0 -> fp32 d_out (final, no epilogue extras)
  layer_k<<<gL, WG, 0, stream>>>(G0, slot, cnt_in, nsrc, W2, b2, nullptr, out,
                                 n, 0, 0u, 0u);
}

// Round 10
// 261.467 us; speedup vs baseline: 16.5546x; 1.0117x over previous
//
#include <hip/hip_runtime.h>
#include <hip/hip_bf16.h>
#include <hip/hip_fp16.h>
#include <cstddef>

// ---------------------------------------------------------------------------
// GCN: 3x GraphConv(norm='both') + relu + threefry dropout (p=0.5)
//   Aggregate-first identity: ndst (A (nsrc.h) W) == ndst (A (nsrc.h)) W.
//   Gather buffers G are FP16 row-major; all accumulation stays FP32.
//
//   r10 = r9 + three density/decoupling fixes (no structural gambles):
//   1) EXACT bucket-local CSR slot: r9's SLOT_S=48-padded rows (192B stride,
//      ~64B used = 33% line utilization) wasted ~12MB of the 84MB/layer
//      L2-miss traffic. role_k dst-role now scans counts into 4-padded
//      bucket-local offsets, packs meta[v]=(off<<8)|deg, scatters into a
//      dense slot[b*BCAPE+off] run. slot 19.3->8MB, layer slot reads dense.
//   2) binbufS u16 (r9 needlessly stored dst; src role only reads srcloc).
//   3) layer_k: single barrier after Ws staging; rows LDS hand-off is
//      same-wave only -> s_waitcnt lgkmcnt(0)+sched_barrier instead of
//      __syncthreads -> waves decouple post-gather (FMA/threefry of a
//      finished wave overlaps siblings' gathers).
//   Model (r4-r9): gather floor = L2-miss random-128B service rate
//   (~2.2TB/s); 84MB -> ~40us. All occupancy/VALU/structure attacks null;
//   push-mode (r8) and feature-slicing (r6) negative. Only traffic cuts pay.
//   History: r1/r8 per-feature global atomics = 7.5-65x write amp; r4
//   threefry hoist serialized; r5 split neutral.
// ---------------------------------------------------------------------------

#define EB 4096        // edges per bin_k block
#define SUBCAP 1280    // per-(bucket,xcdgroup) sub-run cap (E=1020, +8 sigma)
#define NB_SHIFT 9
#define NB_W 512       // nodes per bucket
#define BCAPE 10240    // per-bucket dense CSR capacity (E=8163+pad, +14 sigma)
#define WG 256

__host__ __device__ static inline unsigned rotl32(unsigned x, int r) {
  return (x << r) | (x >> (32 - r));
}

// JAX threefry2x32 block cipher (20 rounds), matches jax/_src/prng.py lowering.
__host__ __device__ static inline void threefry2x32(unsigned k0, unsigned k1,
                                                    unsigned x0, unsigned x1,
                                                    unsigned& o0, unsigned& o1) {
  unsigned ks2 = k0 ^ k1 ^ 0x1BD11BDAu;
  x0 += k0; x1 += k1;
#define TF_ROUND(r) { x0 += x1; x1 = rotl32(x1, r); x1 ^= x0; }
  TF_ROUND(13) TF_ROUND(15) TF_ROUND(26) TF_ROUND(6)
  x0 += k1;  x1 += ks2 + 1u;
  TF_ROUND(17) TF_ROUND(29) TF_ROUND(16) TF_ROUND(24)
  x0 += ks2; x1 += k0 + 2u;
  TF_ROUND(13) TF_ROUND(15) TF_ROUND(26) TF_ROUND(6)
  x0 += k0;  x1 += k1 + 3u;
  TF_ROUND(17) TF_ROUND(29) TF_ROUND(16) TF_ROUND(24)
  x0 += k1;  x1 += ks2 + 4u;
  TF_ROUND(13) TF_ROUND(15) TF_ROUND(26) TF_ROUND(6)
  x0 += ks2; x1 += k0 + 5u;
#undef TF_ROUND
  o0 = x0; o1 = x1;
}

__device__ static inline float2 h2f(unsigned u) {
  return __half22float2(__builtin_bit_cast(__half2, u));
}
__device__ static inline unsigned f2h(float a, float b) {
  return __builtin_bit_cast(unsigned, __floats2half2_rn(a, b));
}

// ---- pass 1: dual LDS counting-sort -> dense per-(bucket,xcdgrp) sub-runs -
// dst record: (dstloc 9b << 17) | src 17b.  src record: srcloc u16.

__global__ __launch_bounds__(1024) void bin_k(
    const int* __restrict__ src, const int* __restrict__ dst,
    unsigned* __restrict__ binbufD, unsigned short* __restrict__ binbufS,
    int* __restrict__ cursD, int* __restrict__ cursS, int e) {
  __shared__ int hist_d[256], scan_d[256], curs_d[256], gpos_d[256];
  __shared__ int hist_s[256], scan_s[256], curs_s[256], gpos_s[256];
  __shared__ unsigned sorted_d[EB];
  __shared__ unsigned short sorted_s[EB];
  __shared__ unsigned char sbk_d[EB], sbk_s[EB];
  int tid = threadIdx.x, blk = blockIdx.x;
  int base = blk * EB;
  int cnt = e - base;
  if (cnt > EB) cnt = EB;
  int x = blk & 7;

  if (tid < 256) { hist_d[tid] = 0; hist_s[tid] = 0; }
  __syncthreads();
  for (int i = tid; i < cnt; i += 1024) {
    atomicAdd(&hist_d[dst[base + i] >> NB_SHIFT], 1);
    atomicAdd(&hist_s[src[base + i] >> NB_SHIFT], 1);
  }
  __syncthreads();
  int hd = 0, hs = 0;
  if (tid < 256) {
    hd = hist_d[tid]; scan_d[tid] = hd;
    hs = hist_s[tid]; scan_s[tid] = hs;
  }
  __syncthreads();
  for (int st = 1; st < 256; st <<= 1) {
    int ad = 0, as = 0;
    if (tid < 256 && tid >= st) { ad = scan_d[tid - st]; as = scan_s[tid - st]; }
    __syncthreads();
    if (tid < 256) { scan_d[tid] += ad; scan_s[tid] += as; }
    __syncthreads();
  }
  if (tid < 256) { curs_d[tid] = scan_d[tid] - hd; curs_s[tid] = scan_s[tid] - hs; }
  __syncthreads();
  for (int i = tid; i < cnt; i += 1024) {
    int s = src[base + i];
    int d = dst[base + i];
    int bd = d >> NB_SHIFT;
    int pd = atomicAdd(&curs_d[bd], 1);
    sorted_d[pd] = ((unsigned)(d & (NB_W - 1)) << 17) | (unsigned)s;
    sbk_d[pd] = (unsigned char)bd;
    int bs = s >> NB_SHIFT;
    int ps = atomicAdd(&curs_s[bs], 1);
    sorted_s[ps] = (unsigned short)(s & (NB_W - 1));
    sbk_s[ps] = (unsigned char)bs;
  }
  __syncthreads();
  if (tid < 256) {
    int c = hist_d[tid];
    gpos_d[tid] = (c > 0) ? atomicAdd(&cursD[x * 256 + tid], c) : 0;
    c = hist_s[tid];
    gpos_s[tid] = (c > 0) ? atomicAdd(&cursS[x * 256 + tid], c) : 0;
  }
  __syncthreads();
  for (int i = tid; i < cnt; i += 1024) {
    int b = sbk_d[i];
    int gp = gpos_d[b] + (i - (scan_d[b] - hist_d[b]));
    if (gp < SUBCAP)   // overflow prob ~1e-10
      binbufD[((size_t)b * 8 + x) * SUBCAP + gp] = sorted_d[i];
    b = sbk_s[i];
    gp = gpos_s[b] + (i - (scan_s[b] - hist_s[b]));
    if (gp < SUBCAP)
      binbufS[((size_t)b * 8 + x) * SUBCAP + gp] = sorted_s[i];
  }
}

// ---- pass 2: per-bucket dense-run consumption ------------------------------
// b < nbuck: dst role -> dense bucket-local CSR (slot runs + meta).
// else: src role -> nsrc + fp16 G0 prescale.

__global__ __launch_bounds__(1024) void role_k(
    const unsigned* __restrict__ binbufD,
    const unsigned short* __restrict__ binbufS,
    const int* __restrict__ cursD, const int* __restrict__ cursS,
    int* __restrict__ slot, unsigned* __restrict__ meta,
    float* __restrict__ nsrc, const float* __restrict__ x,
    unsigned short* __restrict__ G0, int n, int nbuck) {
  __shared__ int lcur[NB_W];
  __shared__ int loff[NB_W];
  __shared__ float lns[NB_W];
  __shared__ int cx[8];
  int tid = threadIdx.x;
  int bb = blockIdx.x;
  int role = (bb < nbuck) ? 0 : 1;
  int b = role ? (bb - nbuck) : bb;

  const int* cursX = role ? cursS : cursD;
  if (tid < 8) {
    int c = cursX[tid * 256 + b];
    cx[tid] = (c > SUBCAP) ? SUBCAP : c;
  }
  for (int i = tid; i < NB_W; i += 1024) lcur[i] = 0;
  __syncthreads();

  if (role == 0) {
    // pass A: in-degree count per bucket-local node
    for (int xx = 0; xx < 8; ++xx) {
      int c = cx[xx];
      const unsigned* sp = binbufD + ((size_t)b * 8 + xx) * SUBCAP;
      for (int i = tid; i < c; i += 1024) atomicAdd(&lcur[sp[i] >> 17], 1);
    }
    __syncthreads();
    // exclusive scan of 4-padded counts -> bucket-local CSR offsets
    int c4 = 0;
    if (tid < NB_W) { c4 = (lcur[tid] + 3) & ~3; loff[tid] = c4; }
    __syncthreads();
    for (int st = 1; st < NB_W; st <<= 1) {
      int a = 0;
      if (tid < NB_W && tid >= st) a = loff[tid - st];
      __syncthreads();
      if (tid < NB_W) loff[tid] += a;
      __syncthreads();
    }
    if (tid < NB_W) {
      int off = loff[tid] - c4;          // exclusive
      loff[tid] = off;
      int v = (b << NB_SHIFT) + tid;
      if (v < n) {
        int dg = lcur[tid]; if (dg > 255) dg = 255;
        unsigned of = (off < BCAPE) ? (unsigned)off : 0u;
        meta[v] = (of << 8) | (unsigned)dg;
      }
    }
    __syncthreads();
    for (int i = tid; i < NB_W; i += 1024) lcur[i] = 0;
    __syncthreads();
    // pass B: scatter edges to dense bucket-local CSR (runs L2-hot)
    size_t sbase = (size_t)b * BCAPE;
    for (int xx = 0; xx < 8; ++xx) {
      int c = cx[xx];
      const unsigned* sp = binbufD + ((size_t)b * 8 + xx) * SUBCAP;
      for (int i = tid; i < c; i += 1024) {
        unsigned vv = sp[i];
        int dl = vv >> 17;
        int s = (int)(vv & 0x1FFFFu);
        int cc = atomicAdd(&lcur[dl], 1);
        int p = loff[dl] + cc;
        if (p < BCAPE) slot[sbase + p] = s;
      }
    }
  } else {
    // src role: u16 srcloc hist -> nsrc + fp16 G0 = nsrc*x prescale
    for (int xx = 0; xx < 8; ++xx) {
      int c = cx[xx];
      const unsigned short* sp = binbufS + ((size_t)b * 8 + xx) * SUBCAP;
      for (int i = tid; i < c; i += 1024) atomicAdd(&lcur[sp[i]], 1);
    }
    __syncthreads();
    int vbase = b << NB_SHIFT;
    for (int i = tid; i < NB_W; i += 1024) {
      int v = vbase + i;
      if (v < n) {
        int c = lcur[i];
        float ns = (c > 0) ? rsqrtf((float)c) : 0.f;
        lns[i] = ns;
        nsrc[v] = ns;
      }
    }
    __syncthreads();
    const float4* x4 = (const float4*)x;
    uint2* G2 = (uint2*)G0;
    for (int idx = tid; idx < NB_W * 16; idx += 1024) {
      int i = idx >> 4;
      int v = vbase + i;
      if (v < n) {
        float ns = lns[i];
        float4 r = x4[(size_t)v * 16 + (idx & 15)];
        G2[(size_t)v * 16 + (idx & 15)] =
            make_uint2(f2h(r.x * ns, r.y * ns), f2h(r.z * ns, r.w * ns));
      }
    }
  }
}

// ---- fused per-layer kernel: fp16 gather -> fp32 @W -> epilogue -----------
// Wave = 4 nodes (16-lane group per node). Dense CSR: meta[v]=(off<<8)|deg,
// slot run at slot[(v>>9)*BCAPE + off]. Single barrier (Ws staging) before
// gather; rows hand-off is same-wave -> lgkmcnt(0)+sched_barrier only, so
// waves decouple after their own gather.
__global__ __launch_bounds__(WG) void layer_k(
    const unsigned short* __restrict__ G, const int* __restrict__ slot,
    const unsigned* __restrict__ meta, const float* __restrict__ nsrc,
    const float* __restrict__ W, const float* __restrict__ bias,
    unsigned short* __restrict__ GoutH, float* __restrict__ GoutF,
    int n, int mid, unsigned dk0, unsigned dk1) {
  __shared__ float4 Ws[1024];                  // 16 KB W[k][j]
  __shared__ __align__(16) float rows[4][272]; // 4 waves x (4 rows @ 68)
  const float4* W4 = (const float4*)W;
  for (int i = threadIdx.x; i < 1024; i += WG) Ws[i] = W4[i];
  __syncthreads();   // Ws visible to all waves; only barrier in the kernel

  int wave = threadIdx.x >> 6;
  int lane = threadIdx.x & 63;
  int g = lane >> 4;
  int l16 = lane & 15;
  int v = blockIdx.x * 16 + wave * 4 + g;
  bool valid = (v < n);
  int vc = valid ? v : (n - 1);

  unsigned mt = meta[vc];
  int degt = valid ? (int)(mt & 255u) : 0;
  int deg = degt;
  const int* sl = slot + (size_t)(vc >> NB_SHIFT) * BCAPE + (mt >> 8);
  const uint2* G2 = (const uint2*)G;

  float4 aA = make_float4(0.f, 0.f, 0.f, 0.f);
  float4 aB = make_float4(0.f, 0.f, 0.f, 0.f);
  float4 aC = make_float4(0.f, 0.f, 0.f, 0.f);
  float4 aD = make_float4(0.f, 0.f, 0.f, 0.f);
#define ACC(dst, m) { float2 lo = h2f((m).x), hi = h2f((m).y); \
    dst.x += lo.x; dst.y += lo.y; dst.z += hi.x; dst.w += hi.y; }
  int nq = deg >> 2;
  int i = 0;
  for (; i + 1 < nq; i += 2) {   // 2 quads = 8 gathers in flight per group
    int4 q0 = *(const int4*)(sl + i * 4);
    int4 q1 = *(const int4*)(sl + i * 4 + 4);
    uint2 m0 = G2[(size_t)q0.x * 16 + l16];
    uint2 m1 = G2[(size_t)q0.y * 16 + l16];
    uint2 m2 = G2[(size_t)q0.z * 16 + l16];
    uint2 m3 = G2[(size_t)q0.w * 16 + l16];
    uint2 m4 = G2[(size_t)q1.x * 16 + l16];
    uint2 m5 = G2[(size_t)q1.y * 16 + l16];
    uint2 m6 = G2[(size_t)q1.z * 16 + l16];
    uint2 m7 = G2[(size_t)q1.w * 16 + l16];
    ACC(aA, m0) ACC(aB, m1) ACC(aC, m2) ACC(aD, m3)
    ACC(aA, m4) ACC(aB, m5) ACC(aC, m6) ACC(aD, m7)
  }
  if (i < nq) {
    int4 q0 = *(const int4*)(sl + i * 4);
    uint2 m0 = G2[(size_t)q0.x * 16 + l16];
    uint2 m1 = G2[(size_t)q0.y * 16 + l16];
    uint2 m2 = G2[(size_t)q0.z * 16 + l16];
    uint2 m3 = G2[(size_t)q0.w * 16 + l16];
    ACC(aA, m0) ACC(aB, m1) ACC(aC, m2) ACC(aD, m3)
  }
  int rem = deg & 3;
  if (rem) {   // fma-masked tail quad; run 4-padded -> memory-safe
    int4 qq = *(const int4*)(sl + (deg & ~3));
    int s0 = qq.x;                        // rem >= 1
    int s1 = (rem > 1) ? qq.y : s0;
    int s2 = (rem > 2) ? qq.z : s0;
    float w1 = (rem > 1) ? 1.f : 0.f;
    float w2 = (rem > 2) ? 1.f : 0.f;
    uint2 m0 = G2[(size_t)s0 * 16 + l16];
    uint2 m1 = G2[(size_t)s1 * 16 + l16];
    uint2 m2 = G2[(size_t)s2 * 16 + l16];
    ACC(aA, m0)
    { float2 lo = h2f(m1.x), hi = h2f(m1.y);
      aB.x = fmaf(w1, lo.x, aB.x); aB.y = fmaf(w1, lo.y, aB.y);
      aB.z = fmaf(w1, hi.x, aB.z); aB.w = fmaf(w1, hi.y, aB.w); }
    { float2 lo = h2f(m2.x), hi = h2f(m2.y);
      aC.x = fmaf(w2, lo.x, aC.x); aC.y = fmaf(w2, lo.y, aC.y);
      aC.z = fmaf(w2, hi.x, aC.z); aC.w = fmaf(w2, hi.y, aC.w); }
  }
#undef ACC
  float4 agg;
  agg.x = (aA.x + aB.x) + (aC.x + aD.x);
  agg.y = (aA.y + aB.y) + (aC.y + aD.y);
  agg.z = (aA.z + aB.z) + (aC.z + aD.z);
  agg.w = (aA.w + aB.w) + (aC.w + aD.w);

  float* rw = &rows[wave][g * 68];
  *(float4*)(rw + l16 * 4) = agg;
  // same-wave LDS hand-off: lockstep + lgkmcnt(0) suffices (no __syncthreads)
  asm volatile("s_waitcnt lgkmcnt(0)" ::: "memory");
  __builtin_amdgcn_sched_barrier(0);

  float4 acc = make_float4(0.f, 0.f, 0.f, 0.f);
#pragma unroll
  for (int k = 0; k < 64; ++k) {
    float a = rw[k];
    float4 w = Ws[k * 16 + l16];
    acc.x = fmaf(a, w.x, acc.x);
    acc.y = fmaf(a, w.y, acc.y);
    acc.z = fmaf(a, w.z, acc.z);
    acc.w = fmaf(a, w.w, acc.w);
  }

  float nd = (degt > 0) ? rsqrtf((float)degt) : 0.f;
  float4 b4 = ((const float4*)bias)[l16];
  float4 o;
  o.x = fmaf(acc.x, nd, b4.x);
  o.y = fmaf(acc.y, nd, b4.y);
  o.z = fmaf(acc.z, nd, b4.z);
  o.w = fmaf(acc.w, nd, b4.w);
  if (mid) {
    o.x = fmaxf(o.x, 0.f); o.y = fmaxf(o.y, 0.f);
    o.z = fmaxf(o.z, 0.f); o.w = fmaxf(o.w, 0.f);
    unsigned idx = (unsigned)(v * 64 + l16 * 4);
    unsigned r0a, r0b, r1a, r1b, r2a, r2b, r3a, r3b;
    threefry2x32(dk0, dk1, 0u, idx + 0u, r0a, r0b);
    threefry2x32(dk0, dk1, 0u, idx + 1u, r1a, r1b);
    threefry2x32(dk0, dk1, 0u, idx + 2u, r2a, r2b);
    threefry2x32(dk0, dk1, 0u, idx + 3u, r3a, r3b);
    float ns2 = 2.f * nsrc[vc];   // dropout keep-scale x next-layer nsrc
    o.x = ((r0a ^ r0b) & 0x80000000u) ? 0.f : o.x * ns2;
    o.y = ((r1a ^ r1b) & 0x80000000u) ? 0.f : o.y * ns2;
    o.z = ((r2a ^ r2b) & 0x80000000u) ? 0.f : o.z * ns2;
    o.w = ((r3a ^ r3b) & 0x80000000u) ? 0.f : o.w * ns2;
    if (valid)
      ((uint2*)GoutH)[(size_t)v * 16 + l16] =
          make_uint2(f2h(o.x, o.y), f2h(o.z, o.w));
  } else {
    if (valid) ((float4*)GoutF)[(size_t)v * 16 + l16] = o;
  }
}

// ---------------------------------------------------------------------------

extern "C" void kernel_launch(void* const* d_in, const int* in_sizes, int n_in,
                              void* d_out, int out_size, void* d_ws, size_t ws_size,
                              hipStream_t stream) {
  const float* x  = (const float*)d_in[0];
  const float* W0 = (const float*)d_in[1];
  const float* b0 = (const float*)d_in[2];
  const float* W1 = (const float*)d_in[3];
  const float* b1 = (const float*)d_in[4];
  const float* W2 = (const float*)d_in[5];
  const float* b2 = (const float*)d_in[6];
  const int* src  = (const int*)d_in[7];
  const int* dst  = (const int*)d_in[8];
  float* out = (float*)d_out;

  const int n = in_sizes[0] / 64;   // 100000
  const int e = in_sizes[7];        // 1600000
  const int nbuck = (n + NB_W - 1) / NB_W;   // 196
  const int nblk = (e + EB - 1) / EB;        // 391

  char* w = (char*)d_ws;
  size_t off = 0;
  auto alloc = [&](size_t bytes) -> void* {
    void* p = w + off;
    off += (bytes + 255) & ~(size_t)255;
    return p;
  };
  unsigned*       meta    = (unsigned*)alloc((size_t)n * 4);
  float*          nsrc    = (float*)alloc((size_t)n * 4);
  int*            cursD   = (int*)alloc((size_t)8 * 256 * 4);
  int*            cursS   = (int*)alloc((size_t)8 * 256 * 4);
  unsigned*       binbufD = (unsigned*)alloc((size_t)nbuck * 8 * SUBCAP * 4); // 8.0 MB
  unsigned short* binbufS = (unsigned short*)alloc((size_t)nbuck * 8 * SUBCAP * 2); // 4.0 MB
  int*            slot    = (int*)alloc((size_t)nbuck * BCAPE * 4);           // 8.0 MB
  unsigned short* G0      = (unsigned short*)alloc((size_t)n * 64 * 2);       // 12.8 MB
  unsigned short* G1      = (unsigned short*)alloc((size_t)n * 64 * 2);       // 12.8 MB

  unsigned k0a, k0b, k1a, k1b;
  threefry2x32(0u, 1u, 0u, 0u, k0a, k0b);
  threefry2x32(0u, 1u, 0u, 1u, k1a, k1b);

  const int gL = (n + 15) / 16;   // layer: 16 nodes/block

  hipMemsetAsync(cursD, 0, (size_t)8 * 256 * 4, stream);
  hipMemsetAsync(cursS, 0, (size_t)8 * 256 * 4, stream);

  bin_k<<<nblk, 1024, 0, stream>>>(src, dst, binbufD, binbufS,
                                   cursD, cursS, e);
  role_k<<<2 * nbuck, 1024, 0, stream>>>(binbufD, binbufS, cursD, cursS,
                                         slot, meta, nsrc, x, G0, n, nbuck);

  // layer 0: gather G0 -> fp16 G1   (relu+drop key0, x 2*nsrc)
  layer_k<<<gL, WG, 0, stream>>>(G0, slot, meta, nsrc, W0, b0, G1, nullptr,
                                 n, 1, k0a, k0b);
  // layer 1: gather G1 -> fp16 G0   (relu+drop key1, x 2*nsrc)
  layer_k<<<gL, WG, 0, stream>>>(G1, slot, meta, nsrc, W1, b1, G0, nullptr,
                                 n, 1, k1a, k1b);
  // layer 2: gather G0 -> fp32 d_out (final, no epilogue extras)
  layer_k<<<gL, WG, 0, stream>>>(G0, slot, meta, nsrc, W2, b2, nullptr, out,
                                 n, 0, 0u, 0u);
}